// Round 7
// baseline (401.446 us; speedup 1.0000x reference)
//
#include <hip/hip_runtime.h>
#include <math.h>

#define Vc 25
// DKH^-0.5 * log2(e): logits live in log2-space so softmax exp is a bare
// v_exp_f32 (softmax is invariant to the common log2e factor through q).
#define QSCALE 0.5100697243f
#define NITEMS 3200

// may_alias: punned onto the unsigned short LDS/ws arrays (TBAA safety).
typedef short bf16x8 __attribute__((ext_vector_type(8), may_alias));
typedef unsigned int u32x2a __attribute__((ext_vector_type(2), may_alias));
typedef float f32x4 __attribute__((ext_vector_type(4)));

#define FENCE() asm volatile("" ::: "memory")

// RNE (prep path only — off the critical kernel)
__device__ __forceinline__ unsigned short f2bf(float f) {
    unsigned u = __builtin_bit_cast(unsigned, f);
    u = (u + 0x7fff + ((u >> 16) & 1)) >> 16;
    return (unsigned short)u;
}
// fast round-to-nearest (ties away): 2 VALU
__device__ __forceinline__ unsigned short f2bf_fast(float f) {
    unsigned u = __builtin_bit_cast(unsigned, f) + 0x8000u;
    return (unsigned short)(u >> 16);
}
// pack two floats -> two bf16 in one u32: 2 add + 1 perm
__device__ __forceinline__ unsigned pkbf(float lo, float hi) {
    unsigned a = __builtin_bit_cast(unsigned, lo) + 0x8000u;
    unsigned b = __builtin_bit_cast(unsigned, hi) + 0x8000u;
    return __builtin_amdgcn_perm(b, a, 0x07060302);   // D = [b.hi16 : a.hi16]
}
__device__ __forceinline__ float bf2f(unsigned short h) {
    unsigned u = ((unsigned)h) << 16;
    return __builtin_bit_cast(float, u);
}

// 16-lane butterfly add via DPP (xor1, xor2, xor7, xor15 — wider steps valid
// because narrower steps make the groups uniform first). No DS-pipe traffic.
template<int CTRL>
__device__ __forceinline__ float dpp_add(float x) {
    int xi = __builtin_bit_cast(int, x);
    int yi = __builtin_amdgcn_update_dpp(0, xi, CTRL, 0xf, 0xf, true);
    return x + __builtin_bit_cast(float, yi);
}
__device__ __forceinline__ float row_sum16(float s) {
    s = dpp_add<0xB1>(s);    // quad_perm [1,0,3,2]  = xor 1
    s = dpp_add<0x4E>(s);    // quad_perm [2,3,0,1]  = xor 2
    s = dpp_add<0x141>(s);   // row_half_mirror      = xor 7
    s = dpp_add<0x140>(s);   // row_mirror           = xor 15
    return s;
}

// ---------------- ws layout (u16 element offsets) ----------------
#define WQA_O 0        // 12288: qkv weight A-frags [12 mt][2 ks][64 lane][8], q pre-scaled
#define BQ_O  12288    // 384 u16 = 192 f32 bias (q part pre-scaled)
#define KRT_O 12672    // 1088: key_rel [136 m][8 d], rows >=127 zeroed
#define WOA_O 13760    // 4096: out-proj A-frags [2 g][4 mt][64 lane][8], K=32 dense
#define CNT_O 17856    // 2 u16 = 1 u32 work-stealing counter (byte 35712, 4-aligned)

// ---------------- prep: weight swizzle into d_ws (runs every call) ----------------
__global__ void prep_kernel(const float* __restrict__ w_qkv, const float* __restrict__ b_qkv,
                            const float* __restrict__ w_out, const float* __restrict__ key_rel,
                            unsigned short* __restrict__ ws)
{
    const int gid = blockIdx.x * 256 + threadIdx.x;
    const int gsz = gridDim.x * 256;
    if (gid == 0) *(unsigned*)(ws + CNT_O) = 0u;   // reset stealing counter
    for (int id = gid; id < 12288; id += gsz) {
        int j = id & 7, lane = (id >> 3) & 63, ks = (id >> 9) & 1, mt = id >> 10;
        int m = mt * 16 + (lane & 15);
        int k = ks * 32 + (lane >> 4) * 8 + j;
        ws[WQA_O + id] = f2bf(w_qkv[m * 64 + k] * (m < 64 ? QSCALE : 1.f));
    }
    float* bq = (float*)(ws + BQ_O);
    for (int id = gid; id < 192; id += gsz)
        bq[id] = b_qkv[id] * (id < 64 ? QSCALE : 1.f);
    for (int id = gid; id < 1088; id += gsz) {
        int d = id & 7, m = id >> 3;
        ws[KRT_O + id] = (m < 127) ? f2bf(key_rel[m * 8 + d]) : (unsigned short)0;
    }
    for (int id = gid; id < 4096; id += gsz) {
        int j = id & 7, lane = (id >> 3) & 63, mtg = id >> 9;   // mtg = g*4+mt
        int m = (mtg & 3) * 16 + (lane & 15);
        int k = (mtg >> 2) * 32 + (lane >> 4) * 8 + j;
        ws[WOA_O + id] = f2bf(w_out[m * 64 + k]);
    }
}

// ---------------- LDS layout (u16 offsets), 19968 u16 = 39936 B -> 4 blocks/CU ----------------
// Zero-init of [0, SCR_O) is LOAD-BEARING for pad slots (e.g. OT cols 32-39 read
// by bo but never written) — zeroed once pre-loop, stores never dirty the pads.
// Rel logits never touch LDS (ds_bpermute gather) — scratch is ATTL/XST only.
#define QT_O   0       // [8 h]*512 + t*8 + d
#define KT_O   4096    // same layout for k
#define VS_O   8192    // [8 h]*576 + d*72 + t
#define OT_O   12800   // [64 t][40]
#define SCR_O  15360   // 4 x 1152 per-wave scratch: ATTL [16 t][72] / XST alias
#define SMEM_U16 19968

__global__ __launch_bounds__(256, 4)
void tcn_attn(const float* __restrict__ x, const float* __restrict__ b_out,
              const unsigned short* __restrict__ ws, unsigned* __restrict__ cnt,
              float* __restrict__ y)
{
    __shared__ unsigned short sm[SMEM_U16];
    __shared__ unsigned s_item;

    const int tid  = threadIdx.x;
    const int lane = tid & 63;
    const int w    = tid >> 6;
    const int li   = lane & 15;
    const int lq   = lane >> 4;
    const int koff = lq * 8;
    const int trow = 16 * w + li;
    const unsigned scr = SCR_O + w * 1152;

    const bf16x8 z8 = {0,0,0,0,0,0,0,0};
    const f32x4  z4 = {0.f,0.f,0.f,0.f};

    // ---- zero-init [0, SCR_O) with b128 stores: 1920 slots of 8 u16 (once) ----
    for (int i = tid; i < 1920; i += 256)
        *(bf16x8*)(sm + i * 8) = z8;

    // ---- item-invariant state, hoisted out of the work loop ----
    // out-proj bias per (mt,r)
    float bias_r[16];
    #pragma unroll
    for (int mt = 0; mt < 4; ++mt)
        #pragma unroll
        for (int r = 0; r < 4; ++r)
            bias_r[mt * 4 + r] = b_out[mt * 16 + lq * 4 + r];

    // key_rel B-frags (head-invariant, prep-zeroed rows >=127)
    bf16x8 br[5];
    #pragma unroll
    for (int j = 0; j < 5; ++j)
        br[j] = *(const bf16x8*)(ws + KRT_O + (16 * (3 - w + j) + li) * 8 + koff);

    // rel gather = pure 16-lane crossbar: dest (li,lq; nt,r) needs rel row
    // m' = 16nt + li - 4lq - r + 15 at col tl = 4lq+r. Source value is
    // rl[m'>>4][r] of lane (m'&15, same lq) -> 5 bpermutes per r + cndmask.
    int bidx[4];     // bpermute byte index (same for all j at fixed r)
    bool ghi[4];     // m' crossed into the next 16-row window (j = nt+1)
    #pragma unroll
    for (int r = 0; r < 4; ++r) {
        int d = li - 4 * lq - r + 15;          // 0..30
        bidx[r] = ((lane & 48) | (d & 15)) << 2;
        ghi[r]  = d >= 16;
    }

    // front(h): aq/bk loads + QK^T and rel MFMAs into registers
    auto FRONT = [&](int h, f32x4* qk, f32x4* rl) {
        bf16x8 aq = *(const bf16x8*)(sm + QT_O + h * 512 + trow * 8 + koff);
        if (lane >= 16) aq = z8;                 // K=8 real; zero quadrants 1-3
        #pragma unroll
        for (int nt = 0; nt < 4; ++nt) {
            bf16x8 bk = *(const bf16x8*)(sm + KT_O + h * 512 + (16 * nt + li) * 8 + koff);
            qk[nt] = __builtin_amdgcn_mfma_f32_16x16x32_bf16(aq, bk, z4, 0, 0, 0);
        }
        #pragma unroll
        for (int j = 0; j < 5; ++j)
            rl[j] = __builtin_amdgcn_mfma_f32_16x16x32_bf16(aq, br[j], z4, 0, 0, 0);
    };

    const unsigned short* wq = ws + WQA_O;
    const float* bq = (const float*)(ws + BQ_O);

    // ================= persistent work-stealing loop =================
    // item = n*400 + (n1*25 + v): the 25 v-siblings of one (n,n1) tile are
    // CONSECUTIVE items -> grabbed nearly simultaneously -> their scattered
    // 4B y-stores assemble full cache lines in the die-level L3 (write-merge),
    // and their shared x-tile reads hit L2/L3 while hot.
    for (;;) {
        if (tid == 0) s_item = atomicAdd(cnt, 1u);
        __syncthreads();
        const unsigned item = s_item;
        if (item >= NITEMS) break;

        const int n  = item / 400;
        const int bb = item - n * 400;
        const int n1 = bb / 25;
        const int v  = bb - n1 * 25;
        const int t0 = n * 64;

        // ---- single x read: residual prefetch doubles as the staging source ----
        float xres[16];
        f32x4 pacc[4];
        #pragma unroll
        for (int mt = 0; mt < 4; ++mt)
            #pragma unroll
            for (int r = 0; r < 4; ++r) {
                int o = mt * 16 + lq * 4 + r;
                xres[mt * 4 + r] = x[((n1 * 64 + o) * 512 + t0 + 16 * w + li) * Vc + v];
                pacc[mt][r] = bias_r[mt * 4 + r];
            }

        // ---- stage x tile -> XST [t][72] bf16 directly from xres.
        // thread (w,li,lq) holds t = 16w+li, c = mt*16+4lq+r: bijective cover.
        #pragma unroll
        for (int mt = 0; mt < 4; ++mt)
            #pragma unroll
            for (int r = 0; r < 4; ++r)
                sm[SCR_O + (16 * w + li) * 72 + mt * 16 + 4 * lq + r] = f2bf_fast(xres[mt * 4 + r]);
        __syncthreads();

        // ---- qkv via MFMA; A-frags from prep-swizzled ws; packed b64 writes ----
        #pragma unroll
        for (int sec = 0; sec < 3; ++sec) {
            const int mt = sec * 4 + w;
            bf16x8 a0 = *(const bf16x8*)(wq + ((mt * 2 + 0) * 64 + lane) * 8);
            bf16x8 a1 = *(const bf16x8*)(wq + ((mt * 2 + 1) * 64 + lane) * 8);
            f32x4 acc[4];
            #pragma unroll
            for (int nt = 0; nt < 4; ++nt) {
                #pragma unroll
                for (int r = 0; r < 4; ++r) acc[nt][r] = bq[mt * 16 + lq * 4 + r];
                bf16x8 b0 = *(const bf16x8*)(sm + SCR_O + (16 * nt + li) * 72 + koff);
                bf16x8 b1 = *(const bf16x8*)(sm + SCR_O + (16 * nt + li) * 72 + 32 + koff);
                acc[nt] = __builtin_amdgcn_mfma_f32_16x16x32_bf16(a0, b0, acc[nt], 0, 0, 0);
                acc[nt] = __builtin_amdgcn_mfma_f32_16x16x32_bf16(a1, b1, acc[nt], 0, 0, 0);
            }
            const int h2 = 2 * w + (lq >> 1);
            if (sec < 2) {
                const unsigned base = (sec == 0 ? QT_O : KT_O) + h2 * 512 + (lq & 1) * 4;
                #pragma unroll
                for (int nt = 0; nt < 4; ++nt) {
                    u32x2a p;
                    p.x = pkbf(acc[nt][0], acc[nt][1]);
                    p.y = pkbf(acc[nt][2], acc[nt][3]);
                    *(u32x2a*)(sm + base + (16 * nt + li) * 8) = p;   // ds_write_b64
                }
            } else {
                #pragma unroll
                for (int nt = 0; nt < 4; ++nt)
                    #pragma unroll
                    for (int r = 0; r < 4; ++r)
                        sm[VS_O + h2 * 576 + ((lq & 1) * 4 + r) * 72 + 16 * nt + li] = f2bf_fast(acc[nt][r]);
            }
        }
        __syncthreads();
        // ======== barrier-free until next item ========

        f32x4 qk[4], rl[5];
        FRONT(0, qk, rl);

        #pragma unroll
        for (int h = 0; h < 8; ++h) {
            // pipeline: next head's front work overlaps this head's softmax
            f32x4 qkn[4], rln[5];
            if (h < 7) FRONT(h + 1, qkn, rln);
            // prefetch out-proj A-frags from ws (consumed after AV)
            bf16x8 ao[4];
            if ((h & 3) == 3) {
                const int g = h >> 2;
                #pragma unroll
                for (int mt = 0; mt < 4; ++mt)
                    ao[mt] = *(const bf16x8*)(ws + WOA_O + ((g * 4 + mt) * 64 + lane) * 8);
            }
            // gather rel via ds_bpermute (register crossbar, no LDS array)
            float ex[4][4], lsum[4] = {0.f, 0.f, 0.f, 0.f};
            #pragma unroll
            for (int r = 0; r < 4; ++r) {
                float sr[5];
                #pragma unroll
                for (int j = 0; j < 5; ++j)
                    sr[j] = __builtin_bit_cast(float,
                            __builtin_amdgcn_ds_bpermute(bidx[r], __builtin_bit_cast(int, rl[j][r])));
                #pragma unroll
                for (int nt = 0; nt < 4; ++nt) {
                    float rv = ghi[r] ? sr[nt + 1] : sr[nt];
                    float e = __builtin_amdgcn_exp2f(qk[nt][r] + rv);
                    ex[nt][r] = e;
                    lsum[r] += e;
                }
            }
            float linv[4];
            #pragma unroll
            for (int r = 0; r < 4; ++r)
                linv[r] = 1.0f / row_sum16(lsum[r]);
            // UNNORMALIZED att -> ATTL [tl][72] (1/sum folded into OT store)
            #pragma unroll
            for (int nt = 0; nt < 4; ++nt)
                #pragma unroll
                for (int r = 0; r < 4; ++r)
                    sm[scr + (4 * lq + r) * 72 + 16 * nt + li] = f2bf_fast(ex[nt][r]);
            FENCE();   // ATTL stores before AV frag reads
            // AV
            f32x4 av = z4;
            #pragma unroll
            for (int ks = 0; ks < 2; ++ks) {
                bf16x8 aa = *(const bf16x8*)(sm + scr + li * 72 + ks * 32 + koff);
                bf16x8 bv = *(const bf16x8*)(sm + VS_O + h * 576 + (li & 7) * 72 + ks * 32 + koff);
                av = __builtin_amdgcn_mfma_f32_16x16x32_bf16(aa, bv, av, 0, 0, 0);
            }
            if (li < 8) {
                #pragma unroll
                for (int r = 0; r < 4; ++r)
                    sm[OT_O + (16 * w + 4 * lq + r) * 40 + (h & 3) * 8 + li] = f2bf_fast(av[r] * linv[r]);
            }
            // out-proj every 4 heads: K=32 dense, accumulates in pacc
            if ((h & 3) == 3) {
                FENCE();   // OT stores before bo read
                bf16x8 bo = *(const bf16x8*)(sm + OT_O + trow * 40 + koff);
                #pragma unroll
                for (int mt = 0; mt < 4; ++mt)
                    pacc[mt] = __builtin_amdgcn_mfma_f32_16x16x32_bf16(ao[mt], bo, pacc[mt], 0, 0, 0);
            }
            FENCE();   // next head's ATTL stores stay below this head's AV/OT reads
            if (h < 7) {
                #pragma unroll
                for (int i = 0; i < 4; ++i) qk[i] = qkn[i];
                #pragma unroll
                for (int j = 0; j < 5; ++j) rl[j] = rln[j];
            }
        }

        // ---- epilogue: residual (prefetched fp32) + relu ----
        #pragma unroll
        for (int mt = 0; mt < 4; ++mt)
            #pragma unroll
            for (int r = 0; r < 4; ++r) {
                int o = mt * 16 + lq * 4 + r;
                int idx = ((n1 * 64 + o) * 512 + t0 + 16 * w + li) * Vc + v;
                y[idx] = fmaxf(pacc[mt][r] + xres[mt * 4 + r], 0.f);
            }
    }
}

extern "C" void kernel_launch(void* const* d_in, const int* in_sizes, int n_in,
                              void* d_out, int out_size, void* d_ws, size_t ws_size,
                              hipStream_t stream) {
    const float* x       = (const float*)d_in[0];
    const float* w_qkv   = (const float*)d_in[1];
    const float* b_qkv   = (const float*)d_in[2];
    const float* w_out   = (const float*)d_in[3];
    const float* b_out   = (const float*)d_in[4];
    const float* key_rel = (const float*)d_in[5];
    float* y = (float*)d_out;
    unsigned short* ws = (unsigned short*)d_ws;
    unsigned* cnt = (unsigned*)(ws + CNT_O);

    prep_kernel<<<dim3(96), dim3(256), 0, stream>>>(w_qkv, b_qkv, w_out, key_rel, ws);
    // 1024 persistent blocks = 4/CU x 256 CU, work-stealing over 3200 items
    tcn_attn<<<dim3(1024), dim3(256), 0, stream>>>(x, b_out, ws, cnt, y);
}

// Round 9
// 211.946 us; speedup vs baseline: 1.8941x; 1.8941x over previous
//
#include <hip/hip_runtime.h>
#include <math.h>

#define Vc 25
// DKH^-0.5 * log2(e): logits live in log2-space so softmax exp is a bare
// v_exp_f32 (softmax is invariant to the common log2e factor through q).
#define QSCALE 0.5100697243f

// may_alias: punned onto the unsigned short LDS/ws arrays (TBAA safety).
typedef short bf16x8 __attribute__((ext_vector_type(8), may_alias));
typedef unsigned int u32x2a __attribute__((ext_vector_type(2), may_alias));
typedef float f32x4 __attribute__((ext_vector_type(4)));

#define FENCE() asm volatile("" ::: "memory")

// RNE (prep path only — off the critical kernel)
__device__ __forceinline__ unsigned short f2bf(float f) {
    unsigned u = __builtin_bit_cast(unsigned, f);
    u = (u + 0x7fff + ((u >> 16) & 1)) >> 16;
    return (unsigned short)u;
}
// fast round-to-nearest (ties away): 2 VALU
__device__ __forceinline__ unsigned short f2bf_fast(float f) {
    unsigned u = __builtin_bit_cast(unsigned, f) + 0x8000u;
    return (unsigned short)(u >> 16);
}
// pack two floats -> two bf16 in one u32: 2 add + 1 perm
__device__ __forceinline__ unsigned pkbf(float lo, float hi) {
    unsigned a = __builtin_bit_cast(unsigned, lo) + 0x8000u;
    unsigned b = __builtin_bit_cast(unsigned, hi) + 0x8000u;
    return __builtin_amdgcn_perm(b, a, 0x07060302);   // D = [b.hi16 : a.hi16]
}
__device__ __forceinline__ float bf2f(unsigned short h) {
    unsigned u = ((unsigned)h) << 16;
    return __builtin_bit_cast(float, u);
}

// 16-lane butterfly add via DPP (xor1, xor2, xor7, xor15 — wider steps valid
// because narrower steps make the groups uniform first). No DS-pipe traffic.
template<int CTRL>
__device__ __forceinline__ float dpp_add(float x) {
    int xi = __builtin_bit_cast(int, x);
    int yi = __builtin_amdgcn_update_dpp(0, xi, CTRL, 0xf, 0xf, true);
    return x + __builtin_bit_cast(float, yi);
}
__device__ __forceinline__ float row_sum16(float s) {
    s = dpp_add<0xB1>(s);    // quad_perm [1,0,3,2]  = xor 1
    s = dpp_add<0x4E>(s);    // quad_perm [2,3,0,1]  = xor 2
    s = dpp_add<0x141>(s);   // row_half_mirror      = xor 7
    s = dpp_add<0x140>(s);   // row_mirror           = xor 15
    return s;
}

// ---------------- ws layout (u16 element offsets) ----------------
#define WQA_O 0        // 12288: qkv weight A-frags [12 mt][2 ks][64 lane][8], q pre-scaled
#define BQ_O  12288    // 384 u16 = 192 f32 bias (q part pre-scaled)
#define KRT_O 12672    // 1088: key_rel [136 m][8 d], rows >=127 zeroed
#define WOA_O 13760    // 4096: out-proj A-frags [2 g][4 mt][64 lane][8], K=32 dense

// ---------------- prep: weight swizzle into d_ws (runs every call) ----------------
__global__ void prep_kernel(const float* __restrict__ w_qkv, const float* __restrict__ b_qkv,
                            const float* __restrict__ w_out, const float* __restrict__ key_rel,
                            unsigned short* __restrict__ ws)
{
    const int gid = blockIdx.x * 256 + threadIdx.x;
    const int gsz = gridDim.x * 256;
    for (int id = gid; id < 12288; id += gsz) {
        int j = id & 7, lane = (id >> 3) & 63, ks = (id >> 9) & 1, mt = id >> 10;
        int m = mt * 16 + (lane & 15);
        int k = ks * 32 + (lane >> 4) * 8 + j;
        ws[WQA_O + id] = f2bf(w_qkv[m * 64 + k] * (m < 64 ? QSCALE : 1.f));
    }
    float* bq = (float*)(ws + BQ_O);
    for (int id = gid; id < 192; id += gsz)
        bq[id] = b_qkv[id] * (id < 64 ? QSCALE : 1.f);
    for (int id = gid; id < 1088; id += gsz) {
        int d = id & 7, m = id >> 3;
        ws[KRT_O + id] = (m < 127) ? f2bf(key_rel[m * 8 + d]) : (unsigned short)0;
    }
    for (int id = gid; id < 4096; id += gsz) {
        int j = id & 7, lane = (id >> 3) & 63, mtg = id >> 9;   // mtg = g*4+mt
        int m = (mtg & 3) * 16 + (lane & 15);
        int k = (mtg >> 2) * 32 + (lane >> 4) * 8 + j;
        ws[WOA_O + id] = f2bf(w_out[m * 64 + k]);
    }
}

// ---------------- LDS layout (u16 offsets), 19968 u16 = 39936 B -> 4 blocks/CU ----------------
// Zero-init of [0, SCR_O) is LOAD-BEARING: B-frag b128 reads over-read into pad
// slots (nulled by zero A-quadrants) — every reachable byte must be zeroed-or-written.
// (FRONT's bk b128 over-read past KT lands in VS, which is fully written pre-sync.)
// Rel logits never touch LDS (ds_bpermute gather) — scratch is ATTL/XST only.
// NOTE: grid (8,400) geometry is LOAD-BEARING for memory traffic: linear block id
// = b*8+n puts the 25 v-siblings of a tile at spacing 200 = 0 mod 8 -> same XCD,
// so shared x lines are fetched once and y lines assemble in one L2 (R7 lesson).
#define QT_O   0       // [8 h]*512 + t*8 + d
#define KT_O   4096    // same layout for k
#define VS_O   8192    // [8 h]*576 + d*72 + t
#define OT_O   12800   // [64 t][40]
#define SCR_O  15360   // 4 x 1152 per-wave scratch: ATTL [16 t][72] / XST alias
#define SMEM_U16 19968

__global__ __launch_bounds__(256, 4)
void tcn_attn(const float* __restrict__ x, const float* __restrict__ b_out,
              const unsigned short* __restrict__ ws, float* __restrict__ y)
{
    __shared__ unsigned short sm[SMEM_U16];

    const int tid  = threadIdx.x;
    const int lane = tid & 63;
    const int w    = tid >> 6;
    const int li   = lane & 15;
    const int lq   = lane >> 4;
    const int koff = lq * 8;
    const int n    = blockIdx.x;
    const int b    = blockIdx.y;
    const int n1   = b / Vc;
    const int v    = b - n1 * Vc;
    const int t0   = n * 64;
    const int trow = 16 * w + li;
    const unsigned scr = SCR_O + w * 1152;

    const bf16x8 z8 = {0,0,0,0,0,0,0,0};
    const f32x4  z4 = {0.f,0.f,0.f,0.f};

    // ---- zero-init [0, SCR_O) with b128 stores: 1920 slots of 8 u16 ----
    for (int i = tid; i < 1920; i += 256)
        *(bf16x8*)(sm + i * 8) = z8;

    // ---- single x read: residual prefetch doubles as the staging source ----
    float xres[16];
    f32x4 pacc[4];
    #pragma unroll
    for (int mt = 0; mt < 4; ++mt)
        #pragma unroll
        for (int r = 0; r < 4; ++r) {
            int o = mt * 16 + lq * 4 + r;
            xres[mt * 4 + r] = x[((n1 * 64 + o) * 512 + t0 + 16 * w + li) * Vc + v];
            pacc[mt][r] = b_out[o];
        }

    // ---- stage x tile -> XST [t][72] bf16 directly from xres (no 2nd global read).
    // thread (w,li,lq) holds t = 16w+li, c = mt*16+4lq+r: bijective tile cover.
    #pragma unroll
    for (int mt = 0; mt < 4; ++mt)
        #pragma unroll
        for (int r = 0; r < 4; ++r)
            sm[SCR_O + (16 * w + li) * 72 + mt * 16 + 4 * lq + r] = f2bf_fast(xres[mt * 4 + r]);
    __syncthreads();

    // ---- qkv via MFMA; A-frags from prep-swizzled ws; packed b64 writes to QT/KT ----
    const unsigned short* wq = ws + WQA_O;
    const float* bq = (const float*)(ws + BQ_O);
    #pragma unroll
    for (int sec = 0; sec < 3; ++sec) {
        const int mt = sec * 4 + w;
        bf16x8 a0 = *(const bf16x8*)(wq + ((mt * 2 + 0) * 64 + lane) * 8);
        bf16x8 a1 = *(const bf16x8*)(wq + ((mt * 2 + 1) * 64 + lane) * 8);
        f32x4 acc[4];
        __builtin_amdgcn_s_setprio(1);
        #pragma unroll
        for (int nt = 0; nt < 4; ++nt) {
            #pragma unroll
            for (int r = 0; r < 4; ++r) acc[nt][r] = bq[mt * 16 + lq * 4 + r];
            bf16x8 b0 = *(const bf16x8*)(sm + SCR_O + (16 * nt + li) * 72 + koff);
            bf16x8 b1 = *(const bf16x8*)(sm + SCR_O + (16 * nt + li) * 72 + 32 + koff);
            acc[nt] = __builtin_amdgcn_mfma_f32_16x16x32_bf16(a0, b0, acc[nt], 0, 0, 0);
            acc[nt] = __builtin_amdgcn_mfma_f32_16x16x32_bf16(a1, b1, acc[nt], 0, 0, 0);
        }
        __builtin_amdgcn_s_setprio(0);
        const int h2 = 2 * w + (lq >> 1);
        if (sec < 2) {
            const unsigned base = (sec == 0 ? QT_O : KT_O) + h2 * 512 + (lq & 1) * 4;
            #pragma unroll
            for (int nt = 0; nt < 4; ++nt) {
                u32x2a p;
                p.x = pkbf(acc[nt][0], acc[nt][1]);
                p.y = pkbf(acc[nt][2], acc[nt][3]);
                *(u32x2a*)(sm + base + (16 * nt + li) * 8) = p;   // ds_write_b64
            }
        } else {
            #pragma unroll
            for (int nt = 0; nt < 4; ++nt)
                #pragma unroll
                for (int r = 0; r < 4; ++r)
                    sm[VS_O + h2 * 576 + ((lq & 1) * 4 + r) * 72 + 16 * nt + li] = f2bf_fast(acc[nt][r]);
        }
    }
    __syncthreads();
    // ======== no more barriers ========

    // key_rel B-frags (head-invariant, prep-zeroed rows >=127)
    bf16x8 br[5];
    #pragma unroll
    for (int j = 0; j < 5; ++j)
        br[j] = *(const bf16x8*)(ws + KRT_O + (16 * (3 - w + j) + li) * 8 + koff);

    // rel gather = pure 16-lane crossbar: dest (li,lq; nt,r) needs rel row
    // m' = 16nt + li - 4lq - r + 15 at col tl = 4lq+r. Source value is
    // rl[m'>>4][r] of lane (m'&15, same lq) -> 5 bpermutes per r + cndmask.
    int bidx[4];     // bpermute byte index (same for all j at fixed r)
    bool ghi[4];     // m' crossed into the next 16-row window (j = nt+1)
    #pragma unroll
    for (int r = 0; r < 4; ++r) {
        int d = li - 4 * lq - r + 15;          // 0..30
        bidx[r] = ((lane & 48) | (d & 15)) << 2;
        ghi[r]  = d >= 16;
    }

    // front(h): aq/bk loads + QK^T and rel MFMAs into registers
    auto FRONT = [&](int h, f32x4* qk, f32x4* rl) {
        bf16x8 aq = *(const bf16x8*)(sm + QT_O + h * 512 + trow * 8 + koff);
        if (lane >= 16) aq = z8;                 // K=8 real; zero quadrants 1-3
        __builtin_amdgcn_s_setprio(1);
        #pragma unroll
        for (int nt = 0; nt < 4; ++nt) {
            bf16x8 bk = *(const bf16x8*)(sm + KT_O + h * 512 + (16 * nt + li) * 8 + koff);
            qk[nt] = __builtin_amdgcn_mfma_f32_16x16x32_bf16(aq, bk, z4, 0, 0, 0);
        }
        #pragma unroll
        for (int j = 0; j < 5; ++j)
            rl[j] = __builtin_amdgcn_mfma_f32_16x16x32_bf16(aq, br[j], z4, 0, 0, 0);
        __builtin_amdgcn_s_setprio(0);
    };

    f32x4 qk[4], rl[5];
    FRONT(0, qk, rl);

    #pragma unroll
    for (int h = 0; h < 8; ++h) {
        // pipeline: next head's front work overlaps this head's softmax
        f32x4 qkn[4], rln[5];
        if (h < 7) FRONT(h + 1, qkn, rln);
        // prefetch out-proj A-frags from ws (consumed after AV)
        bf16x8 ao[4];
        if ((h & 3) == 3) {
            const int g = h >> 2;
            #pragma unroll
            for (int mt = 0; mt < 4; ++mt)
                ao[mt] = *(const bf16x8*)(ws + WOA_O + ((g * 4 + mt) * 64 + lane) * 8);
        }
        // gather rel via ds_bpermute + exp2 + IMMEDIATE ATTL store (UNNORMALIZED;
        // 1/sum folded into OT store). Storing e before the row-reduce lets the
        // ds_write drain + AV's read latency overlap the DPP chain. ATTL is
        // wave-private and per-wave DS ops complete in order -> no HW fence needed.
        float lsum[4] = {0.f, 0.f, 0.f, 0.f};
        #pragma unroll
        for (int r = 0; r < 4; ++r) {
            float sr[5];
            #pragma unroll
            for (int j = 0; j < 5; ++j)
                sr[j] = __builtin_bit_cast(float,
                        __builtin_amdgcn_ds_bpermute(bidx[r], __builtin_bit_cast(int, rl[j][r])));
            #pragma unroll
            for (int nt = 0; nt < 4; ++nt) {
                float rv = ghi[r] ? sr[nt + 1] : sr[nt];
                float e = __builtin_amdgcn_exp2f(qk[nt][r] + rv);
                sm[scr + (4 * lq + r) * 72 + 16 * nt + li] = f2bf_fast(e);
                lsum[r] += e;
            }
        }
        float linv[4];
        #pragma unroll
        for (int r = 0; r < 4; ++r)
            linv[r] = 1.0f / row_sum16(lsum[r]);
        FENCE();   // ATTL stores stay above AV frag reads (compiler ordering)
        // AV
        f32x4 av = z4;
        __builtin_amdgcn_s_setprio(1);
        #pragma unroll
        for (int ks = 0; ks < 2; ++ks) {
            bf16x8 aa = *(const bf16x8*)(sm + scr + li * 72 + ks * 32 + koff);
            bf16x8 bv = *(const bf16x8*)(sm + VS_O + h * 576 + (li & 7) * 72 + ks * 32 + koff);
            av = __builtin_amdgcn_mfma_f32_16x16x32_bf16(aa, bv, av, 0, 0, 0);
        }
        __builtin_amdgcn_s_setprio(0);
        if (li < 8) {
            #pragma unroll
            for (int r = 0; r < 4; ++r)
                sm[OT_O + (16 * w + 4 * lq + r) * 40 + (h & 3) * 8 + li] = f2bf_fast(av[r] * linv[r]);
        }
        // out-proj every 4 heads: K=32 dense, accumulates in pacc
        if ((h & 3) == 3) {
            FENCE();   // OT stores before bo read
            bf16x8 bo = *(const bf16x8*)(sm + OT_O + trow * 40 + koff);
            __builtin_amdgcn_s_setprio(1);
            #pragma unroll
            for (int mt = 0; mt < 4; ++mt)
                pacc[mt] = __builtin_amdgcn_mfma_f32_16x16x32_bf16(ao[mt], bo, pacc[mt], 0, 0, 0);
            __builtin_amdgcn_s_setprio(0);
        }
        FENCE();   // next head's ATTL stores stay below this head's AV/OT reads
        if (h < 7) {
            #pragma unroll
            for (int i = 0; i < 4; ++i) qk[i] = qkn[i];
            #pragma unroll
            for (int j = 0; j < 5; ++j) rl[j] = rln[j];
        }
    }

    // ---- epilogue: residual (prefetched fp32) + relu ----
    #pragma unroll
    for (int mt = 0; mt < 4; ++mt)
        #pragma unroll
        for (int r = 0; r < 4; ++r) {
            int o = mt * 16 + lq * 4 + r;
            int idx = ((n1 * 64 + o) * 512 + t0 + 16 * w + li) * Vc + v;
            y[idx] = fmaxf(pacc[mt][r] + xres[mt * 4 + r], 0.f);
        }
}

extern "C" void kernel_launch(void* const* d_in, const int* in_sizes, int n_in,
                              void* d_out, int out_size, void* d_ws, size_t ws_size,
                              hipStream_t stream) {
    const float* x       = (const float*)d_in[0];
    const float* w_qkv   = (const float*)d_in[1];
    const float* b_qkv   = (const float*)d_in[2];
    const float* w_out   = (const float*)d_in[3];
    const float* b_out   = (const float*)d_in[4];
    const float* key_rel = (const float*)d_in[5];
    float* y = (float*)d_out;
    unsigned short* ws = (unsigned short*)d_ws;

    prep_kernel<<<dim3(96), dim3(256), 0, stream>>>(w_qkv, b_qkv, w_out, key_rel, ws);
    dim3 grid(512 / 64, 400);   // (8, 400) — geometry load-bearing, see LDS note
    tcn_attn<<<grid, dim3(256), 0, stream>>>(x, b_out, ws, y);
}

// Round 10
// 203.488 us; speedup vs baseline: 1.9728x; 1.0416x over previous
//
#include <hip/hip_runtime.h>
#include <math.h>

#define Vc 25
// DKH^-0.5 * log2(e): logits live in log2-space so softmax exp is a bare
// v_exp_f32 (softmax is invariant to the common log2e factor through q).
#define QSCALE 0.5100697243f

#if __has_builtin(__builtin_amdgcn_mfma_f32_16x16x16bf16_1k)
#define HAVE_MFMA16 1
#define MFMA16(a, b, c) __builtin_amdgcn_mfma_f32_16x16x16bf16_1k(a, b, c, 0, 0, 0)
#else
#define HAVE_MFMA16 0
#endif

// may_alias: punned onto the unsigned short LDS/ws arrays (TBAA safety).
typedef short bf16x8 __attribute__((ext_vector_type(8), may_alias));
typedef short bf16x4 __attribute__((ext_vector_type(4), may_alias));
typedef unsigned int u32x2a __attribute__((ext_vector_type(2), may_alias));
typedef float f32x4 __attribute__((ext_vector_type(4)));

#define FENCE() asm volatile("" ::: "memory")

// RNE (prep path only — off the critical kernel)
__device__ __forceinline__ unsigned short f2bf(float f) {
    unsigned u = __builtin_bit_cast(unsigned, f);
    u = (u + 0x7fff + ((u >> 16) & 1)) >> 16;
    return (unsigned short)u;
}
// fast round-to-nearest (ties away): 2 VALU
__device__ __forceinline__ unsigned short f2bf_fast(float f) {
    unsigned u = __builtin_bit_cast(unsigned, f) + 0x8000u;
    return (unsigned short)(u >> 16);
}
// pack two floats -> two bf16 in one u32: 2 add + 1 perm
__device__ __forceinline__ unsigned pkbf(float lo, float hi) {
    unsigned a = __builtin_bit_cast(unsigned, lo) + 0x8000u;
    unsigned b = __builtin_bit_cast(unsigned, hi) + 0x8000u;
    return __builtin_amdgcn_perm(b, a, 0x07060302);   // D = [b.hi16 : a.hi16]
}
__device__ __forceinline__ float bf2f(unsigned short h) {
    unsigned u = ((unsigned)h) << 16;
    return __builtin_bit_cast(float, u);
}

// 16-lane butterfly add via DPP (xor1, xor2, xor7, xor15 — wider steps valid
// because narrower steps make the groups uniform first). No DS-pipe traffic.
template<int CTRL>
__device__ __forceinline__ float dpp_add(float x) {
    int xi = __builtin_bit_cast(int, x);
    int yi = __builtin_amdgcn_update_dpp(0, xi, CTRL, 0xf, 0xf, true);
    return x + __builtin_bit_cast(float, yi);
}
__device__ __forceinline__ float row_sum16(float s) {
    s = dpp_add<0xB1>(s);    // quad_perm [1,0,3,2]  = xor 1
    s = dpp_add<0x4E>(s);    // quad_perm [2,3,0,1]  = xor 2
    s = dpp_add<0x141>(s);   // row_half_mirror      = xor 7
    s = dpp_add<0x140>(s);   // row_mirror           = xor 15
    return s;
}

// ---------------- ws layout (u16 element offsets) ----------------
#define WQA_O 0        // 12288: qkv weight A-frags [12 mt][2 ks][64 lane][8], q pre-scaled
#define BQ_O  12288    // 384 u16 = 192 f32 bias (q part pre-scaled)
#define KRT_O 12672    // 1088: key_rel [136 m][8 d], rows >=127 zeroed
#define WOA_O 13760    // 4096: out-proj A-frags [2 g][4 mt][64 lane][8], K=32 dense

// ---------------- prep: weight swizzle into d_ws (runs every call) ----------------
__global__ void prep_kernel(const float* __restrict__ w_qkv, const float* __restrict__ b_qkv,
                            const float* __restrict__ w_out, const float* __restrict__ key_rel,
                            unsigned short* __restrict__ ws)
{
    const int gid = blockIdx.x * 256 + threadIdx.x;
    const int gsz = gridDim.x * 256;
    for (int id = gid; id < 12288; id += gsz) {
        int j = id & 7, lane = (id >> 3) & 63, ks = (id >> 9) & 1, mt = id >> 10;
        int m = mt * 16 + (lane & 15);
        int k = ks * 32 + (lane >> 4) * 8 + j;
        ws[WQA_O + id] = f2bf(w_qkv[m * 64 + k] * (m < 64 ? QSCALE : 1.f));
    }
    float* bq = (float*)(ws + BQ_O);
    for (int id = gid; id < 192; id += gsz)
        bq[id] = b_qkv[id] * (id < 64 ? QSCALE : 1.f);
    for (int id = gid; id < 1088; id += gsz) {
        int d = id & 7, m = id >> 3;
        ws[KRT_O + id] = (m < 127) ? f2bf(key_rel[m * 8 + d]) : (unsigned short)0;
    }
    for (int id = gid; id < 4096; id += gsz) {
        int j = id & 7, lane = (id >> 3) & 63, mtg = id >> 9;   // mtg = g*4+mt
        int m = (mtg & 3) * 16 + (lane & 15);
        int k = (mtg >> 2) * 32 + (lane >> 4) * 8 + j;
        ws[WOA_O + id] = f2bf(w_out[m * 64 + k]);
    }
}

// ---------------- LDS layout (u16 offsets), 19968 u16 = 39936 B -> 4 blocks/CU ----------------
// Zero-init of [0, SCR_O) is LOAD-BEARING: B-frag b128/b64 reads over-read into pad
// slots (nulled by zero A-quadrants) — every reachable byte must be zeroed-or-written.
// (FRONT's bk tail over-read past KT lands in VS, which is fully written pre-sync.)
// Rel logits never touch LDS (ds_bpermute gather) — scratch is ATTL/XST only.
// NOTE: grid (8,400) geometry is LOAD-BEARING for memory traffic: linear block id
// = b*8+n puts the 25 v-siblings of a tile at spacing 200 = 0 mod 8 -> same XCD,
// so shared x lines are fetched once and y lines assemble in one L2 (R7 lesson).
#define QT_O   0       // [8 h]*512 + t*8 + d
#define KT_O   4096    // same layout for k
#define VS_O   8192    // [8 h]*576 + d*72 + t
#define OT_O   12800   // [64 t][40]
#define SCR_O  15360   // 4 x 1152 per-wave scratch: ATTL [16 t][72] / XST alias
#define SMEM_U16 19968

__global__ __launch_bounds__(256, 4)
void tcn_attn(const float* __restrict__ x, const float* __restrict__ b_out,
              const unsigned short* __restrict__ ws, float* __restrict__ y)
{
    __shared__ unsigned short sm[SMEM_U16];

    const int tid  = threadIdx.x;
    const int lane = tid & 63;
    const int w    = tid >> 6;
    const int li   = lane & 15;
    const int lq   = lane >> 4;
    const int koff = lq * 8;    // k-offset for 16x16x32 frags (u16 elems)
    const int koff4 = lq * 4;   // k-offset for 16x16x16 frags
    const int n    = blockIdx.x;
    const int b    = blockIdx.y;
    const int n1   = b / Vc;
    const int v    = b - n1 * Vc;
    const int t0   = n * 64;
    const int trow = 16 * w + li;
    const unsigned scr = SCR_O + w * 1152;

    const bf16x8 z8 = {0,0,0,0,0,0,0,0};
    const bf16x4 z4h = {0,0,0,0};
    const f32x4  z4 = {0.f,0.f,0.f,0.f};
    (void)z4h; (void)koff4;

    // ---- zero-init [0, SCR_O) with b128 stores: 1920 slots of 8 u16 ----
    for (int i = tid; i < 1920; i += 256)
        *(bf16x8*)(sm + i * 8) = z8;

    // ---- single x read: residual prefetch doubles as the staging source ----
    float xres[16];
    f32x4 pacc[4];
    #pragma unroll
    for (int mt = 0; mt < 4; ++mt)
        #pragma unroll
        for (int r = 0; r < 4; ++r) {
            int o = mt * 16 + lq * 4 + r;
            xres[mt * 4 + r] = x[((n1 * 64 + o) * 512 + t0 + 16 * w + li) * Vc + v];
            pacc[mt][r] = b_out[o];
        }

    // ---- stage x tile -> XST [t][72] bf16 directly from xres (no 2nd global read).
    // thread (w,li,lq) holds t = 16w+li, c = mt*16+4lq+r: bijective tile cover.
    #pragma unroll
    for (int mt = 0; mt < 4; ++mt)
        #pragma unroll
        for (int r = 0; r < 4; ++r)
            sm[SCR_O + (16 * w + li) * 72 + mt * 16 + 4 * lq + r] = f2bf_fast(xres[mt * 4 + r]);
    __syncthreads();

    // ---- qkv via MFMA (16x16x32, K=64 dense); packed b64 writes to QT/KT ----
    const unsigned short* wq = ws + WQA_O;
    const float* bq = (const float*)(ws + BQ_O);
    #pragma unroll
    for (int sec = 0; sec < 3; ++sec) {
        const int mt = sec * 4 + w;
        bf16x8 a0 = *(const bf16x8*)(wq + ((mt * 2 + 0) * 64 + lane) * 8);
        bf16x8 a1 = *(const bf16x8*)(wq + ((mt * 2 + 1) * 64 + lane) * 8);
        f32x4 acc[4];
        __builtin_amdgcn_s_setprio(1);
        #pragma unroll
        for (int nt = 0; nt < 4; ++nt) {
            #pragma unroll
            for (int r = 0; r < 4; ++r) acc[nt][r] = bq[mt * 16 + lq * 4 + r];
            bf16x8 b0 = *(const bf16x8*)(sm + SCR_O + (16 * nt + li) * 72 + koff);
            bf16x8 b1 = *(const bf16x8*)(sm + SCR_O + (16 * nt + li) * 72 + 32 + koff);
            acc[nt] = __builtin_amdgcn_mfma_f32_16x16x32_bf16(a0, b0, acc[nt], 0, 0, 0);
            acc[nt] = __builtin_amdgcn_mfma_f32_16x16x32_bf16(a1, b1, acc[nt], 0, 0, 0);
        }
        __builtin_amdgcn_s_setprio(0);
        const int h2 = 2 * w + (lq >> 1);
        if (sec < 2) {
            const unsigned base = (sec == 0 ? QT_O : KT_O) + h2 * 512 + (lq & 1) * 4;
            #pragma unroll
            for (int nt = 0; nt < 4; ++nt) {
                u32x2a p;
                p.x = pkbf(acc[nt][0], acc[nt][1]);
                p.y = pkbf(acc[nt][2], acc[nt][3]);
                *(u32x2a*)(sm + base + (16 * nt + li) * 8) = p;   // ds_write_b64
            }
        } else {
            #pragma unroll
            for (int nt = 0; nt < 4; ++nt)
                #pragma unroll
                for (int r = 0; r < 4; ++r)
                    sm[VS_O + h2 * 576 + ((lq & 1) * 4 + r) * 72 + 16 * nt + li] = f2bf_fast(acc[nt][r]);
        }
    }
    __syncthreads();
    // ======== no more barriers ========

    // rel gather = pure 16-lane crossbar: dest (li,lq; nt,r) needs rel row
    // m' = 16nt + li - 4lq - r + 15 at col tl = 4lq+r. Source value is
    // rl[m'>>4][r] of lane (m'&15, same lq) -> 5 bpermutes per r + cndmask.
    int bidx[4];     // bpermute byte index (same for all j at fixed r)
    bool ghi[4];     // m' crossed into the next 16-row window (j = nt+1)
    #pragma unroll
    for (int r = 0; r < 4; ++r) {
        int d = li - 4 * lq - r + 15;          // 0..30
        bidx[r] = ((lane & 48) | (d & 15)) << 2;
        ghi[r]  = d >= 16;
    }

#if HAVE_MFMA16
    // key_rel B-frags for 16x16x16 (head-invariant, prep-zeroed rows >=127).
    // k = 4*lq + j; real d = 0..7 -> lq>=2 lanes read next-row garbage, nulled
    // by the zeroed A k-quadrants (lane>=32). Numerics validated in R6 run.
    bf16x4 br4[5];
    #pragma unroll
    for (int j = 0; j < 5; ++j)
        br4[j] = *(const bf16x4*)(ws + KRT_O + (16 * (3 - w + j) + li) * 8 + koff4);

    // front(h): aq/bk b64 loads + QK^T and rel MFMAs (16x16x16: K=8 real of 16,
    // half the fragment bytes of the x32 form; C/D layout identical).
    auto FRONT = [&](int h, f32x4* qk, f32x4* rl) {
        bf16x4 aq = *(const bf16x4*)(sm + QT_O + h * 512 + trow * 8 + koff4);
        if (lane >= 32) aq = z4h;                // K=8 real; zero k-quadrants 2-3
        __builtin_amdgcn_s_setprio(1);
        #pragma unroll
        for (int nt = 0; nt < 4; ++nt) {
            bf16x4 bk = *(const bf16x4*)(sm + KT_O + h * 512 + (16 * nt + li) * 8 + koff4);
            qk[nt] = MFMA16(aq, bk, z4);
        }
        #pragma unroll
        for (int j = 0; j < 5; ++j)
            rl[j] = MFMA16(aq, br4[j], z4);
        __builtin_amdgcn_s_setprio(0);
    };
#else
    // Fallback: proven x32 FRONT (R2/R9 form).
    bf16x8 br[5];
    #pragma unroll
    for (int j = 0; j < 5; ++j)
        br[j] = *(const bf16x8*)(ws + KRT_O + (16 * (3 - w + j) + li) * 8 + koff);

    auto FRONT = [&](int h, f32x4* qk, f32x4* rl) {
        bf16x8 aq = *(const bf16x8*)(sm + QT_O + h * 512 + trow * 8 + koff);
        if (lane >= 16) aq = z8;                 // K=8 real; zero quadrants 1-3
        __builtin_amdgcn_s_setprio(1);
        #pragma unroll
        for (int nt = 0; nt < 4; ++nt) {
            bf16x8 bk = *(const bf16x8*)(sm + KT_O + h * 512 + (16 * nt + li) * 8 + koff);
            qk[nt] = __builtin_amdgcn_mfma_f32_16x16x32_bf16(aq, bk, z4, 0, 0, 0);
        }
        #pragma unroll
        for (int j = 0; j < 5; ++j)
            rl[j] = __builtin_amdgcn_mfma_f32_16x16x32_bf16(aq, br[j], z4, 0, 0, 0);
        __builtin_amdgcn_s_setprio(0);
    };
#endif

    // issue the 20 rel crossbar shuffles for a head (results land in sr[r][j])
    auto BPERM = [&](const f32x4* rl, float (*sr)[5]) {
        #pragma unroll
        for (int r = 0; r < 4; ++r)
            #pragma unroll
            for (int j = 0; j < 5; ++j)
                sr[r][j] = __builtin_bit_cast(float,
                        __builtin_amdgcn_ds_bpermute(bidx[r], __builtin_bit_cast(int, rl[j][r])));
    };

    // prologue: head 0's front + shuffles (rl registers die right after BPERM)
    f32x4 qk[4];
    float sr[4][5];
    {
        f32x4 rl0[5];
        FRONT(0, qk, rl0);
        BPERM(rl0, sr);
    }

    #pragma unroll
    for (int h = 0; h < 8; ++h) {
        // pipeline: next head's front work overlaps this head's softmax
        f32x4 qkn[4], rln[5];
        if (h < 7) FRONT(h + 1, qkn, rln);
        // prefetch out-proj A-frags from ws (consumed after AV)
        bf16x8 ao[4];
        if ((h & 3) == 3) {
            const int g = h >> 2;
            #pragma unroll
            for (int mt = 0; mt < 4; ++mt)
                ao[mt] = *(const bf16x8*)(ws + WOA_O + ((g * 4 + mt) * 64 + lane) * 8);
        }
        // exp2 + IMMEDIATE ATTL store (UNNORMALIZED; 1/sum folded into OT store).
        // Shuffle results sr were issued LAST iteration -> no crossbar wait here.
        float lsum[4] = {0.f, 0.f, 0.f, 0.f};
        #pragma unroll
        for (int r = 0; r < 4; ++r)
            #pragma unroll
            for (int nt = 0; nt < 4; ++nt) {
                float rv = ghi[r] ? sr[r][nt + 1] : sr[r][nt];
                float e = __builtin_amdgcn_exp2f(qk[nt][r] + rv);
                sm[scr + (4 * lq + r) * 72 + 16 * nt + li] = f2bf_fast(e);
                lsum[r] += e;
            }
        float linv[4];
        #pragma unroll
        for (int r = 0; r < 4; ++r)
            linv[r] = 1.0f / row_sum16(lsum[r]);
        FENCE();   // ATTL stores stay above AV frag reads (compiler ordering)
        // AV
        f32x4 av = z4;
        __builtin_amdgcn_s_setprio(1);
        #pragma unroll
        for (int ks = 0; ks < 2; ++ks) {
            bf16x8 aa = *(const bf16x8*)(sm + scr + li * 72 + ks * 32 + koff);
            bf16x8 bv = *(const bf16x8*)(sm + VS_O + h * 576 + (li & 7) * 72 + ks * 32 + koff);
            av = __builtin_amdgcn_mfma_f32_16x16x32_bf16(aa, bv, av, 0, 0, 0);
        }
        __builtin_amdgcn_s_setprio(0);
        // issue next head's shuffles NOW: their ~50cy crossbar latency hides
        // under OT + out-proj + FRONT(h+2); rln dies here (no rl carry).
        float srn[4][5];
        if (h < 7) BPERM(rln, srn);
        if (li < 8) {
            #pragma unroll
            for (int r = 0; r < 4; ++r)
                sm[OT_O + (16 * w + 4 * lq + r) * 40 + (h & 3) * 8 + li] = f2bf_fast(av[r] * linv[r]);
        }
        // out-proj every 4 heads: K=32 dense, accumulates in pacc
        if ((h & 3) == 3) {
            FENCE();   // OT stores before bo read
            bf16x8 bo = *(const bf16x8*)(sm + OT_O + trow * 40 + koff);
            __builtin_amdgcn_s_setprio(1);
            #pragma unroll
            for (int mt = 0; mt < 4; ++mt)
                pacc[mt] = __builtin_amdgcn_mfma_f32_16x16x32_bf16(ao[mt], bo, pacc[mt], 0, 0, 0);
            __builtin_amdgcn_s_setprio(0);
        }
        FENCE();   // next head's ATTL stores stay below this head's AV/OT reads
        if (h < 7) {
            #pragma unroll
            for (int i = 0; i < 4; ++i) qk[i] = qkn[i];
            #pragma unroll
            for (int r = 0; r < 4; ++r)
                #pragma unroll
                for (int j = 0; j < 5; ++j)
                    sr[r][j] = srn[r][j];
        }
    }

    // ---- epilogue: residual (prefetched fp32) + relu ----
    #pragma unroll
    for (int mt = 0; mt < 4; ++mt)
        #pragma unroll
        for (int r = 0; r < 4; ++r) {
            int o = mt * 16 + lq * 4 + r;
            int idx = ((n1 * 64 + o) * 512 + t0 + 16 * w + li) * Vc + v;
            y[idx] = fmaxf(pacc[mt][r] + xres[mt * 4 + r], 0.f);
        }
}

extern "C" void kernel_launch(void* const* d_in, const int* in_sizes, int n_in,
                              void* d_out, int out_size, void* d_ws, size_t ws_size,
                              hipStream_t stream) {
    const float* x       = (const float*)d_in[0];
    const float* w_qkv   = (const float*)d_in[1];
    const float* b_qkv   = (const float*)d_in[2];
    const float* w_out   = (const float*)d_in[3];
    const float* b_out   = (const float*)d_in[4];
    const float* key_rel = (const float*)d_in[5];
    float* y = (float*)d_out;
    unsigned short* ws = (unsigned short*)d_ws;

    prep_kernel<<<dim3(96), dim3(256), 0, stream>>>(w_qkv, b_qkv, w_out, key_rel, ws);
    dim3 grid(512 / 64, 400);   // (8, 400) — geometry load-bearing, see LDS note
    tcn_attn<<<grid, dim3(256), 0, stream>>>(x, b_out, ws, y);
}